// Round 16
// baseline (74.874 us; speedup 1.0000x reference)
//
#include <hip/hip_runtime.h>

#define BATCH 4096
#define DIM   512
#define NROW  8192
#define NCH   32                      // 256-row/col chunks
#define NOFF  496                     // off-diag 256x256 cells (rc<cc)
#define NLIGHT 96                     // 32 diag cells x 3 light 128x128 quarters
#define NSLOT 33

typedef __attribute__((ext_vector_type(8))) short bf16x8;
typedef __attribute__((ext_vector_type(4))) float f32x4;

__device__ inline unsigned short f2bf(float f) {
    unsigned int u = __float_as_uint(f);
    u += 0x7fffu + ((u >> 16) & 1u);
    return (unsigned short)(u >> 16);
}

__device__ __forceinline__ void gload16(const unsigned short* g, unsigned short* l) {
    __builtin_amdgcn_global_load_lds(
        (const __attribute__((address_space(1))) void*)g,
        (__attribute__((address_space(3))) void*)l, 16, 0, 0);
}

// ---------------- Kernel 1: normalize rows + positives ----------------
__global__ __launch_bounds__(256) void normalize_pos_kernel(
    const float* __restrict__ ei, const float* __restrict__ ej,
    unsigned short* __restrict__ reps, float* __restrict__ pos) {
    const int t = threadIdx.x & 63;
    const int i = blockIdx.x * 4 + (threadIdx.x >> 6);

    const float4* ri = (const float4*)(ei + (size_t)i * DIM);
    const float4* rj = (const float4*)(ej + (size_t)i * DIM);
    float4 a0 = ri[t], a1 = ri[t + 64];
    float4 b0 = rj[t], b1 = rj[t + 64];

    float si  = a0.x*a0.x + a0.y*a0.y + a0.z*a0.z + a0.w*a0.w
              + a1.x*a1.x + a1.y*a1.y + a1.z*a1.z + a1.w*a1.w;
    float sj  = b0.x*b0.x + b0.y*b0.y + b0.z*b0.z + b0.w*b0.w
              + b1.x*b1.x + b1.y*b1.y + b1.z*b1.z + b1.w*b1.w;
    float dij = a0.x*b0.x + a0.y*b0.y + a0.z*b0.z + a0.w*b0.w
              + a1.x*b1.x + a1.y*b1.y + a1.z*b1.z + a1.w*b1.w;

    #pragma unroll
    for (int m = 1; m < 64; m <<= 1) {
        si  += __shfl_xor(si,  m);
        sj  += __shfl_xor(sj,  m);
        dij += __shfl_xor(dij, m);
    }
    float invi = 1.0f / fmaxf(sqrtf(si), 1e-12f);
    float invj = 1.0f / fmaxf(sqrtf(sj), 1e-12f);

    ushort4 o0, o1, p0, p1;
    o0.x = f2bf(a0.x*invi); o0.y = f2bf(a0.y*invi); o0.z = f2bf(a0.z*invi); o0.w = f2bf(a0.w*invi);
    o1.x = f2bf(a1.x*invi); o1.y = f2bf(a1.y*invi); o1.z = f2bf(a1.z*invi); o1.w = f2bf(a1.w*invi);
    p0.x = f2bf(b0.x*invj); p0.y = f2bf(b0.y*invj); p0.z = f2bf(b0.z*invj); p0.w = f2bf(b0.w*invj);
    p1.x = f2bf(b1.x*invj); p1.y = f2bf(b1.y*invj); p1.z = f2bf(b1.z*invj); p1.w = f2bf(b1.w*invj);

    ushort4* wi = (ushort4*)(reps + (size_t)i * DIM);
    ushort4* wj = (ushort4*)(reps + (size_t)(BATCH + i) * DIM);
    wi[t] = o0; wi[t + 64] = o1;
    wj[t] = p0; wj[t + 64] = p1;
    if (t == 0) pos[i] = dij * invi * invj;
}

// ---------------- Kernel 2: unified sim kernel --------------------------
// blockIdx < 96: LIGHT 128x128 diag-quarter (r4 decomposition, m97-style
//   single-buffer loop) -- dispatched first, finishes inside round 1.
// blockIdx >= 96: HEAVY 256x256 off-diag cell = r6's measured-best loop
//   (ring-4, depth-3 prefetch, counted vmcnt(8/4/0), lgkm pin, setprio,
//   zero-conflict swizzle). 496 = 2 clean dispatch rounds at 1 block/CU.
__global__ __launch_bounds__(512, 2) void simsum_kernel(
    const unsigned short* __restrict__ reps, float* __restrict__ partials) {
    __shared__ unsigned short lds[4][16384];   // heavy ring-4; light uses lds[0]

    const int tid  = threadIdx.x;
    const int lane = tid & 63;
    const int wave = tid >> 6;
    const int s = lane & 15, q = lane >> 4;
    const int lr = lane >> 2;
    const int g8 = (((lane & 3) ^ ((lane >> 2) & 3) ^ (lane >> 4)) & 3) * 8;
    const int sig = ((s & 3) ^ (s >> 2)) & 3;
    const int koS = ((q ^ sig) & 3) << 4;
    const float SCALE = 2.8853900817779268f;   // 1/(TEMP*ln2) = 2/ln2

    if (blockIdx.x < NLIGHT) {
        // ================= LIGHT: 128x128 diag quarter =================
        const int d = blockIdx.x / 3, sub = blockIdx.x % 3;
        const int rowBase = d * 256 + ((sub == 1) ? 128 : 0);
        const int colBase = d * 256 + ((sub >= 1) ? 128 : 0);
        const bool mask = (sub < 2);
        const int wr = wave >> 2, wc = wave & 3;   // 2M x 4N over 128^2

        const unsigned short* gA = reps + (size_t)(rowBase + wave * 16 + lr) * DIM + g8;
        const unsigned short* gB = reps + (size_t)(colBase + wave * 16 + lr) * DIM + g8;
        const int aoff = (wr * 64 + s) * 64 + koS;           // + m*1024, m=0..3
        const int boff = 8192 + (wc * 32 + s) * 64 + koS;    // + n*1024, n=0..1
        unsigned short* l0 = &lds[0][0];

        f32x4 acc[4][2];
        #pragma unroll
        for (int m = 0; m < 4; ++m)
            #pragma unroll
            for (int n = 0; n < 2; ++n) acc[m][n] = (f32x4){0.f,0.f,0.f,0.f};

        for (int t = 0; t < 16; ++t) {
            __syncthreads();
            gload16(gA + t * 32, l0 + wave * 512);
            gload16(gB + t * 32, l0 + 4096 + wave * 512);
            __syncthreads();
            bf16x8 af[4], bf[2];
            #pragma unroll
            for (int m = 0; m < 4; ++m) af[m] = *(const bf16x8*)((const char*)l0 + aoff + m * 1024);
            #pragma unroll
            for (int n = 0; n < 2; ++n) bf[n] = *(const bf16x8*)((const char*)l0 + boff + n * 1024);
            #pragma unroll
            for (int m = 0; m < 4; ++m)
                #pragma unroll
                for (int n = 0; n < 2; ++n)
                    acc[m][n] = __builtin_amdgcn_mfma_f32_16x16x32_bf16(
                        af[m], bf[n], acc[m][n], 0, 0, 0);
        }

        float* red = (float*)lds;   // [4][128] rowsum | [2][128] colsum
        __syncthreads();
        float colacc[2] = {0.f, 0.f};
        #pragma unroll
        for (int m = 0; m < 4; ++m) {
            const int lrow0 = wr * 64 + m * 16 + (q << 2);
            const int grow0 = rowBase + lrow0;
            float rs[4] = {0.f,0.f,0.f,0.f};
            #pragma unroll
            for (int n = 0; n < 2; ++n) {
                const int gcol = colBase + wc * 32 + n * 16 + s;
                #pragma unroll
                for (int j = 0; j < 4; ++j) {
                    float e = exp2f(acc[m][n][j] * SCALE);
                    if (mask && (grow0 + j == gcol)) e = 0.f;
                    rs[j] += e;
                    colacc[n] += e;
                }
            }
            #pragma unroll
            for (int j = 0; j < 4; ++j) {
                float v = rs[j];
                v += __shfl_xor(v, 1); v += __shfl_xor(v, 2);
                v += __shfl_xor(v, 4); v += __shfl_xor(v, 8);
                if (s == 0) red[wc * 128 + lrow0 + j] = v;
            }
        }
        #pragma unroll
        for (int n = 0; n < 2; ++n) {
            float v = colacc[n];
            v += __shfl_xor(v, 16); v += __shfl_xor(v, 32);
            if (q == 0) red[512 + wr * 128 + wc * 32 + n * 16 + s] = v;
        }
        __syncthreads();
        if (tid < 128) {
            float rsum = red[tid] + red[128 + tid] + red[256 + tid] + red[384 + tid];
            if (sub < 2) {
                partials[(size_t)d * NROW + rowBase + tid] = rsum;   // symmetric quarter
            } else {
                partials[(size_t)32 * NROW + rowBase + tid] = rsum;
                partials[(size_t)32 * NROW + colBase + tid] = red[512 + tid] + red[640 + tid];
            }
        }
        return;
    }

    // ================= HEAVY: r6's off-diag 256x256 loop =================
    const int h = blockIdx.x - NLIGHT;
    int bid = (h & 7) * (NOFF / 8) + (h >> 3);     // 496 = 8*62 bijective
    int rc = 0, b = bid;
    while (b >= NCH - 1 - rc) { b -= NCH - 1 - rc; ++rc; }
    const int cc = rc + 1 + b;                     // rc < cc strictly

    const int wr = wave >> 2, wc = wave & 3;
    const int rowBase = rc * 256, colBase = cc * 256;

    const unsigned short* gAw = reps + (size_t)(rowBase + wave * 32 + lr) * DIM + g8;
    const unsigned short* gBw = reps + (size_t)(colBase + wave * 32 + lr) * DIM + g8;

    const int aoff = (wr * 128 + s) * 64 + koS;                // + m*1024
    const int boff = 16384 + (wc * 64 + s) * 64 + koS;         // + n*1024

    f32x4 acc[8][4];
    #pragma unroll
    for (int m = 0; m < 8; ++m)
        #pragma unroll
        for (int n = 0; n < 4; ++n) acc[m][n] = (f32x4){0.f,0.f,0.f,0.f};

#define STAGE(t) do { \
        const int _kb = (t) * 32; \
        unsigned short* _sb = &lds[(t) & 3][0]; \
        gload16(gAw + _kb,            _sb + wave * 1024); \
        gload16(gAw + 16 * DIM + _kb, _sb + wave * 1024 + 512); \
        gload16(gBw + _kb,            _sb + 8192 + wave * 1024); \
        gload16(gBw + 16 * DIM + _kb, _sb + 8192 + wave * 1024 + 512); \
    } while (0)

    STAGE(0); STAGE(1); STAGE(2);

    #pragma unroll
    for (int t = 0; t < 16; ++t) {
        if (t < 14)       { asm volatile("s_waitcnt vmcnt(8)" ::: "memory"); }
        else if (t == 14) { asm volatile("s_waitcnt vmcnt(4)" ::: "memory"); }
        else              { asm volatile("s_waitcnt vmcnt(0)" ::: "memory"); }
        __builtin_amdgcn_s_barrier();
        __builtin_amdgcn_sched_barrier(0);

        if (t + 3 < 16) STAGE(t + 3);

        const char* base = (const char*)&lds[t & 3][0];
        bf16x8 af[8], bf[4];
        #pragma unroll
        for (int m = 0; m < 8; ++m) af[m] = *(const bf16x8*)(base + aoff + m * 1024);
        #pragma unroll
        for (int n = 0; n < 4; ++n) bf[n] = *(const bf16x8*)(base + boff + n * 1024);

        asm volatile("s_waitcnt lgkmcnt(0)" ::: "memory");
        __builtin_amdgcn_sched_barrier(0);
        __builtin_amdgcn_s_setprio(1);
        #pragma unroll
        for (int m = 0; m < 8; ++m)
            #pragma unroll
            for (int n = 0; n < 4; ++n)
                acc[m][n] = __builtin_amdgcn_mfma_f32_16x16x32_bf16(
                    af[m], bf[n], acc[m][n], 0, 0, 0);
        __builtin_amdgcn_s_setprio(0);
    }
#undef STAGE

    float* red = (float*)lds;                  // [4][256] rowsum | [2][256] colsum
    __syncthreads();
    float colacc[4] = {0.f,0.f,0.f,0.f};
    #pragma unroll
    for (int m = 0; m < 8; ++m) {
        const int lrow0 = wr * 128 + m * 16 + (q << 2);
        float rs[4] = {0.f,0.f,0.f,0.f};
        #pragma unroll
        for (int n = 0; n < 4; ++n)
            #pragma unroll
            for (int j = 0; j < 4; ++j) {
                float e = exp2f(acc[m][n][j] * SCALE);
                rs[j] += e;
                colacc[n] += e;
            }
        #pragma unroll
        for (int j = 0; j < 4; ++j) {
            float v = rs[j];
            v += __shfl_xor(v, 1); v += __shfl_xor(v, 2);
            v += __shfl_xor(v, 4); v += __shfl_xor(v, 8);
            if (s == 0) red[wc * 256 + lrow0 + j] = v;
        }
    }
    #pragma unroll
    for (int n = 0; n < 4; ++n) {
        float v = colacc[n];
        v += __shfl_xor(v, 16); v += __shfl_xor(v, 32);
        if (q == 0) red[1024 + wr * 256 + wc * 64 + n * 16 + s] = v;
    }
    __syncthreads();
    if (tid < 256) {
        partials[(size_t)cc * NROW + rowBase + tid] =
            red[tid] + red[256 + tid] + red[512 + tid] + red[768 + tid];
        partials[(size_t)rc * NROW + colBase + tid] =
            red[1024 + tid] + red[1280 + tid];
    }
}

// ---------------- Kernel 3a: per-row loss partial sums ----------------
__global__ __launch_bounds__(256) void rowloss_kernel(
    const float* __restrict__ partials, const float* __restrict__ pos,
    double* __restrict__ blocksum) {
    const int t = threadIdx.x;
    const int r = blockIdx.x * 256 + t;
    float denom = 0.f;
    #pragma unroll 11
    for (int c = 0; c < NSLOT; ++c)
        denom += partials[(size_t)c * NROW + r];
    double v = (double)(logf(denom) - 2.0f * pos[r & (BATCH - 1)]);
    __shared__ double redl[256];
    redl[t] = v;
    __syncthreads();
    for (int off = 128; off > 0; off >>= 1) {
        if (t < off) redl[t] += redl[t + off];
        __syncthreads();
    }
    if (t == 0) blocksum[blockIdx.x] = redl[0];
}

__global__ void final2_kernel(const double* __restrict__ blocksum,
                              float* __restrict__ out) {
    if (threadIdx.x == 0) {
        double ssum = 0.0;
        #pragma unroll
        for (int i = 0; i < NROW / 256; ++i) ssum += blocksum[i];
        out[0] = (float)(ssum / (double)NROW);
    }
}

extern "C" void kernel_launch(void* const* d_in, const int* in_sizes, int n_in,
                              void* d_out, int out_size, void* d_ws, size_t ws_size,
                              hipStream_t stream) {
    const float* ei = (const float*)d_in[0];
    const float* ej = (const float*)d_in[1];
    float* out = (float*)d_out;

    unsigned short* reps = (unsigned short*)d_ws;                       // 8 MB
    float* pos      = (float*)((char*)d_ws + (size_t)NROW * DIM * 2);   // 16 KB
    float* partials = pos + BATCH;                                      // 33*8192*4
    double* blocksum = (double*)(partials + (size_t)NSLOT * NROW);

    normalize_pos_kernel<<<BATCH / 4, 256, 0, stream>>>(ei, ej, reps, pos);
    simsum_kernel<<<NLIGHT + NOFF, 512, 0, stream>>>(reps, partials);
    rowloss_kernel<<<NROW / 256, 256, 0, stream>>>(partials, pos, blocksum);
    final2_kernel<<<1, 64, 0, stream>>>(blocksum, out);
}

// Round 17
// 64.491 us; speedup vs baseline: 1.1610x; 1.1610x over previous
//
#include <hip/hip_runtime.h>

#define BATCH 4096
#define DIM   512
#define NROW  8192
#define NCH   32                      // 256-row/col chunks
#define NOFF  496                     // off-diag 256x256 cells (rc<cc)
#define NLIGHT 96                     // 32 diag cells x 3 light 128x128 quarters
#define NSLOT 33
#define NT8   8                       // K-steps of 64 bytes (fp8)

typedef __attribute__((ext_vector_type(4))) float f32x4;
typedef __attribute__((ext_vector_type(2))) long long2v;

// ---- f32 -> fp8 e4m3fn RNE (|x|<=1 here; proven r11/r12, absmax 0.0) ----
__device__ inline unsigned f2fp8(float f) {
    unsigned u = __float_as_uint(f);
    unsigned s = (u >> 31) << 7;
    unsigned mag = u & 0x7fffffffu;
    unsigned q = (mag + 0x7FFFFu + ((mag >> 20) & 1u)) >> 20;
    int e8 = (int)(q >> 3) - 120;
    if (e8 >= 1) return s | ((unsigned)e8 << 3) | (q & 7u);
    float t = __uint_as_float(mag) * 512.0f;
    return s | (unsigned)rintf(t);
}

__device__ __forceinline__ void gload16(const unsigned char* g, unsigned char* l) {
    __builtin_amdgcn_global_load_lds(
        (const __attribute__((address_space(1))) void*)g,
        (__attribute__((address_space(3))) void*)l, 16, 0, 0);
}

// ---------------- Kernel 1: normalize rows + positives -> fp8 reps ----------
// K-permuted layout per 64-byte block: byte p = q*16 + h*8 + b holds
// k = b + h*32 + q*8 -> one b128 LDS read = {k<32 half, k>=32 half}.
__global__ __launch_bounds__(256) void normalize_pos_kernel(
    const float* __restrict__ ei, const float* __restrict__ ej,
    unsigned char* __restrict__ reps, float* __restrict__ pos) {
    const int t = threadIdx.x & 63;
    const int i = blockIdx.x * 4 + (threadIdx.x >> 6);

    const float4* ri = (const float4*)(ei + (size_t)i * DIM);
    const float4* rj = (const float4*)(ej + (size_t)i * DIM);
    float4 a0 = ri[t], a1 = ri[t + 64];
    float4 b0 = rj[t], b1 = rj[t + 64];

    float si  = a0.x*a0.x + a0.y*a0.y + a0.z*a0.z + a0.w*a0.w
              + a1.x*a1.x + a1.y*a1.y + a1.z*a1.z + a1.w*a1.w;
    float sj  = b0.x*b0.x + b0.y*b0.y + b0.z*b0.z + b0.w*b0.w
              + b1.x*b1.x + b1.y*b1.y + b1.z*b1.z + b1.w*b1.w;
    float dij = a0.x*b0.x + a0.y*b0.y + a0.z*b0.z + a0.w*b0.w
              + a1.x*b1.x + a1.y*b1.y + a1.z*b1.z + a1.w*b1.w;

    #pragma unroll
    for (int m = 1; m < 64; m <<= 1) {
        si  += __shfl_xor(si,  m);
        sj  += __shfl_xor(sj,  m);
        dij += __shfl_xor(dij, m);
    }
    float invi = 1.0f / fmaxf(sqrtf(si), 1e-12f);
    float invj = 1.0f / fmaxf(sqrtf(sj), 1e-12f);

    const int off0 = (t >> 4) * 64 + ((t >> 1) & 3) * 16 + ((t >> 3) & 1) * 8 + 4 * (t & 1);

    unsigned wa0 = f2fp8(a0.x*invi) | (f2fp8(a0.y*invi) << 8)
                 | (f2fp8(a0.z*invi) << 16) | (f2fp8(a0.w*invi) << 24);
    unsigned wa1 = f2fp8(a1.x*invi) | (f2fp8(a1.y*invi) << 8)
                 | (f2fp8(a1.z*invi) << 16) | (f2fp8(a1.w*invi) << 24);
    unsigned wb0 = f2fp8(b0.x*invj) | (f2fp8(b0.y*invj) << 8)
                 | (f2fp8(b0.z*invj) << 16) | (f2fp8(b0.w*invj) << 24);
    unsigned wb1 = f2fp8(b1.x*invj) | (f2fp8(b1.y*invj) << 8)
                 | (f2fp8(b1.z*invj) << 16) | (f2fp8(b1.w*invj) << 24);

    unsigned char* wi = reps + (size_t)i * DIM;
    unsigned char* wj = reps + (size_t)(BATCH + i) * DIM;
    *(unsigned*)(wi + off0)       = wa0;
    *(unsigned*)(wi + off0 + 256) = wa1;
    *(unsigned*)(wj + off0)       = wb0;
    *(unsigned*)(wj + off0 + 256) = wb1;
    if (t == 0) pos[i] = dij * invi * invj;
}

// ---------------- Kernel 2: unified fp8 sim kernel --------------------------
// blockIdx < 496: HEAVY off-diag 256x256 cell (r12's fp8 loop: ring-4,
//   depth-3, counted vmcnt, lgkm pin, L/H-pass MFMA). Dispatched FIRST ->
//   2 clean rounds at 1 block/CU.
// blockIdx >= 496: LIGHT 128x128 diag-quarter (m97-style single buffer),
//   fills round-2 tail.
__global__ __launch_bounds__(512, 2) void simsum_kernel(
    const unsigned char* __restrict__ reps, float* __restrict__ partials) {
    __shared__ unsigned char lds[4][32768];   // heavy ring-4; light uses lds[0]

    const int tid  = threadIdx.x;
    const int lane = tid & 63;
    const int wave = tid >> 6;
    const int s = lane & 15, q = lane >> 4;
    const int lr = lane >> 2;
    const int gb = (((lane & 3) ^ ((lane >> 2) & 3) ^ (lane >> 4)) & 3) * 16;
    const int sig = ((s & 3) ^ (s >> 2)) & 3;
    const int koS = ((q ^ sig) & 3) << 4;
    const float SCALE = 2.8853900817779268f;   // 1/(TEMP*ln2) = 2/ln2

    if (blockIdx.x >= NOFF) {
        // ================= LIGHT: fp8 128x128 diag quarter =================
        const int g = blockIdx.x - NOFF;
        const int d = g / 3, sub = g % 3;
        const int rowBase = d * 256 + ((sub == 1) ? 128 : 0);
        const int colBase = d * 256 + ((sub >= 1) ? 128 : 0);
        const bool mask = (sub < 2);
        const int wr = wave >> 2, wc = wave & 3;   // 2M x 4N over 128^2

        const unsigned char* gA = reps + (size_t)(rowBase + wave * 16 + lr) * DIM + gb;
        const unsigned char* gB = reps + (size_t)(colBase + wave * 16 + lr) * DIM + gb;
        const int aoff = (wr * 64 + s) * 64 + koS;           // + m*1024, m=0..3
        const int boff = 8192 + (wc * 32 + s) * 64 + koS;    // + n*1024, n=0..1
        unsigned char* l0 = &lds[0][0];

        f32x4 acc[4][2];
        #pragma unroll
        for (int m = 0; m < 4; ++m)
            #pragma unroll
            for (int n = 0; n < 2; ++n) acc[m][n] = (f32x4){0.f,0.f,0.f,0.f};

        for (int t = 0; t < NT8; ++t) {
            __syncthreads();
            gload16(gA + t * 64, l0 + wave * 1024);
            gload16(gB + t * 64, l0 + 8192 + wave * 1024);
            __syncthreads();
            long2v af[4], bf[2];
            #pragma unroll
            for (int m = 0; m < 4; ++m) af[m] = *(const long2v*)((const char*)l0 + aoff + m * 1024);
            #pragma unroll
            for (int n = 0; n < 2; ++n) bf[n] = *(const long2v*)((const char*)l0 + boff + n * 1024);
            #pragma unroll
            for (int m = 0; m < 4; ++m)
                #pragma unroll
                for (int n = 0; n < 2; ++n)
                    acc[m][n] = __builtin_amdgcn_mfma_f32_16x16x32_fp8_fp8(
                        af[m][0], bf[n][0], acc[m][n], 0, 0, 0);
            #pragma unroll
            for (int m = 0; m < 4; ++m)
                #pragma unroll
                for (int n = 0; n < 2; ++n)
                    acc[m][n] = __builtin_amdgcn_mfma_f32_16x16x32_fp8_fp8(
                        af[m][1], bf[n][1], acc[m][n], 0, 0, 0);
        }

        float* red = (float*)lds;   // [4][128] rowsum | [2][128] colsum
        __syncthreads();
        float colacc[2] = {0.f, 0.f};
        #pragma unroll
        for (int m = 0; m < 4; ++m) {
            const int lrow0 = wr * 64 + m * 16 + (q << 2);
            const int grow0 = rowBase + lrow0;
            float rs[4] = {0.f,0.f,0.f,0.f};
            #pragma unroll
            for (int n = 0; n < 2; ++n) {
                const int gcol = colBase + wc * 32 + n * 16 + s;
                #pragma unroll
                for (int j = 0; j < 4; ++j) {
                    float e = exp2f(acc[m][n][j] * SCALE);
                    if (mask && (grow0 + j == gcol)) e = 0.f;
                    rs[j] += e;
                    colacc[n] += e;
                }
            }
            #pragma unroll
            for (int j = 0; j < 4; ++j) {
                float v = rs[j];
                v += __shfl_xor(v, 1); v += __shfl_xor(v, 2);
                v += __shfl_xor(v, 4); v += __shfl_xor(v, 8);
                if (s == 0) red[wc * 128 + lrow0 + j] = v;
            }
        }
        #pragma unroll
        for (int n = 0; n < 2; ++n) {
            float v = colacc[n];
            v += __shfl_xor(v, 16); v += __shfl_xor(v, 32);
            if (q == 0) red[512 + wr * 128 + wc * 32 + n * 16 + s] = v;
        }
        __syncthreads();
        if (tid < 128) {
            float rsum = red[tid] + red[128 + tid] + red[256 + tid] + red[384 + tid];
            if (sub < 2) {
                partials[(size_t)d * NROW + rowBase + tid] = rsum;
            } else {
                partials[(size_t)32 * NROW + rowBase + tid] = rsum;
                partials[(size_t)32 * NROW + colBase + tid] = red[512 + tid] + red[640 + tid];
            }
        }
        return;
    }

    // ================= HEAVY: fp8 off-diag 256x256 (r12 loop) =================
    int bid = (blockIdx.x & 7) * (NOFF / 8) + (blockIdx.x >> 3);  // 496 = 8*62
    int rc = 0, b = bid;
    while (b >= NCH - 1 - rc) { b -= NCH - 1 - rc; ++rc; }
    const int cc = rc + 1 + b;                    // rc < cc strictly

    const int wr = wave >> 2, wc = wave & 3;
    const int rowBase = rc * 256, colBase = cc * 256;

    const unsigned char* gAw = reps + (size_t)(rowBase + wave * 32 + lr) * DIM + gb;
    const unsigned char* gBw = reps + (size_t)(colBase + wave * 32 + lr) * DIM + gb;

    const int aoff = (wr * 128 + s) * 64 + koS;                // + m*1024
    const int boff = 16384 + (wc * 64 + s) * 64 + koS;         // + n*1024

    f32x4 acc[8][4];
    #pragma unroll
    for (int m = 0; m < 8; ++m)
        #pragma unroll
        for (int n = 0; n < 4; ++n) acc[m][n] = (f32x4){0.f,0.f,0.f,0.f};

#define STAGE(t) do { \
        const int _kb = (t) * 64; \
        unsigned char* _sb = &lds[(t) & 3][0]; \
        gload16(gAw + _kb,             _sb + wave * 2048); \
        gload16(gAw + 16 * DIM + _kb,  _sb + wave * 2048 + 1024); \
        gload16(gBw + _kb,             _sb + 16384 + wave * 2048); \
        gload16(gBw + 16 * DIM + _kb,  _sb + 16384 + wave * 2048 + 1024); \
    } while (0)

    STAGE(0); STAGE(1); STAGE(2);

    #pragma unroll
    for (int t = 0; t < NT8; ++t) {
        if (t <= 5)       { asm volatile("s_waitcnt vmcnt(8)" ::: "memory"); }
        else if (t == 6)  { asm volatile("s_waitcnt vmcnt(4)" ::: "memory"); }
        else              { asm volatile("s_waitcnt vmcnt(0)" ::: "memory"); }
        __builtin_amdgcn_s_barrier();
        __builtin_amdgcn_sched_barrier(0);

        if (t + 3 < NT8) STAGE(t + 3);

        const char* base = (const char*)&lds[t & 3][0];
        long2v af[8], bf[4];
        #pragma unroll
        for (int m = 0; m < 8; ++m) af[m] = *(const long2v*)(base + aoff + m * 1024);
        #pragma unroll
        for (int n = 0; n < 4; ++n) bf[n] = *(const long2v*)(base + boff + n * 1024);

        asm volatile("s_waitcnt lgkmcnt(0)" ::: "memory");
        __builtin_amdgcn_sched_barrier(0);
        __builtin_amdgcn_s_setprio(1);
        #pragma unroll
        for (int m = 0; m < 8; ++m)
            #pragma unroll
            for (int n = 0; n < 4; ++n)
                acc[m][n] = __builtin_amdgcn_mfma_f32_16x16x32_fp8_fp8(
                    af[m][0], bf[n][0], acc[m][n], 0, 0, 0);
        #pragma unroll
        for (int m = 0; m < 8; ++m)
            #pragma unroll
            for (int n = 0; n < 4; ++n)
                acc[m][n] = __builtin_amdgcn_mfma_f32_16x16x32_fp8_fp8(
                    af[m][1], bf[n][1], acc[m][n], 0, 0, 0);
        __builtin_amdgcn_s_setprio(0);
    }
#undef STAGE

    float* red = (float*)lds;                  // [4][256] rowsum | [2][256] colsum
    __syncthreads();
    float colacc[4] = {0.f,0.f,0.f,0.f};
    #pragma unroll
    for (int m = 0; m < 8; ++m) {
        const int lrow0 = wr * 128 + m * 16 + (q << 2);
        float rs[4] = {0.f,0.f,0.f,0.f};
        #pragma unroll
        for (int n = 0; n < 4; ++n)
            #pragma unroll
            for (int j = 0; j < 4; ++j) {
                float e = exp2f(acc[m][n][j] * SCALE);
                rs[j] += e;
                colacc[n] += e;
            }
        #pragma unroll
        for (int j = 0; j < 4; ++j) {
            float v = rs[j];
            v += __shfl_xor(v, 1); v += __shfl_xor(v, 2);
            v += __shfl_xor(v, 4); v += __shfl_xor(v, 8);
            if (s == 0) red[wc * 256 + lrow0 + j] = v;
        }
    }
    #pragma unroll
    for (int n = 0; n < 4; ++n) {
        float v = colacc[n];
        v += __shfl_xor(v, 16); v += __shfl_xor(v, 32);
        if (q == 0) red[1024 + wr * 256 + wc * 64 + n * 16 + s] = v;
    }
    __syncthreads();
    if (tid < 256) {
        partials[(size_t)cc * NROW + rowBase + tid] =
            red[tid] + red[256 + tid] + red[512 + tid] + red[768 + tid];
        partials[(size_t)rc * NROW + colBase + tid] =
            red[1024 + tid] + red[1280 + tid];
    }
}

// ---------------- Kernel 3a: per-row loss partial sums ----------------
__global__ __launch_bounds__(256) void rowloss_kernel(
    const float* __restrict__ partials, const float* __restrict__ pos,
    double* __restrict__ blocksum) {
    const int t = threadIdx.x;
    const int r = blockIdx.x * 256 + t;
    float denom = 0.f;
    #pragma unroll 11
    for (int c = 0; c < NSLOT; ++c)
        denom += partials[(size_t)c * NROW + r];
    double v = (double)(logf(denom) - 2.0f * pos[r & (BATCH - 1)]);
    __shared__ double redl[256];
    redl[t] = v;
    __syncthreads();
    for (int off = 128; off > 0; off >>= 1) {
        if (t < off) redl[t] += redl[t + off];
        __syncthreads();
    }
    if (t == 0) blocksum[blockIdx.x] = redl[0];
}

__global__ void final2_kernel(const double* __restrict__ blocksum,
                              float* __restrict__ out) {
    if (threadIdx.x == 0) {
        double ssum = 0.0;
        #pragma unroll
        for (int i = 0; i < NROW / 256; ++i) ssum += blocksum[i];
        out[0] = (float)(ssum / (double)NROW);
    }
}

extern "C" void kernel_launch(void* const* d_in, const int* in_sizes, int n_in,
                              void* d_out, int out_size, void* d_ws, size_t ws_size,
                              hipStream_t stream) {
    const float* ei = (const float*)d_in[0];
    const float* ej = (const float*)d_in[1];
    float* out = (float*)d_out;

    unsigned char* reps = (unsigned char*)d_ws;                         // 4 MB fp8
    float* pos      = (float*)((char*)d_ws + (size_t)NROW * DIM);       // 16 KB
    float* partials = pos + BATCH;                                      // 33*8192*4
    double* blocksum = (double*)(partials + (size_t)NSLOT * NROW);

    normalize_pos_kernel<<<BATCH / 4, 256, 0, stream>>>(ei, ej, reps, pos);
    simsum_kernel<<<NOFF + NLIGHT, 512, 0, stream>>>(reps, partials);
    rowloss_kernel<<<NROW / 256, 256, 0, stream>>>(partials, pos, blocksum);
    final2_kernel<<<1, 64, 0, stream>>>(blocksum, out);
}

// Round 18
// 57.286 us; speedup vs baseline: 1.3070x; 1.1258x over previous
//
#include <hip/hip_runtime.h>

#define BATCH 4096
#define DIM   512
#define NROW  8192
#define TILE  128
#define NCH   64                      // 128-row/col chunks
#define NBLK  (NCH * (NCH + 1) / 2)   // 2080 triangle cells (incl. diagonal)
#define NSLOT 64
#define NT8   8                       // K-steps of 64 bytes (fp8)

typedef __attribute__((ext_vector_type(4))) float f32x4;
typedef __attribute__((ext_vector_type(2))) long long2v;

// ---- f32 -> fp8 e4m3fn RNE (|x|<=1 here; proven r11/r12/r17, absmax 0.0) ----
__device__ inline unsigned f2fp8(float f) {
    unsigned u = __float_as_uint(f);
    unsigned s = (u >> 31) << 7;
    unsigned mag = u & 0x7fffffffu;
    unsigned q = (mag + 0x7FFFFu + ((mag >> 20) & 1u)) >> 20;
    int e8 = (int)(q >> 3) - 120;
    if (e8 >= 1) return s | ((unsigned)e8 << 3) | (q & 7u);
    float t = __uint_as_float(mag) * 512.0f;
    return s | (unsigned)rintf(t);
}

__device__ __forceinline__ void gload16(const unsigned char* g, unsigned char* l) {
    __builtin_amdgcn_global_load_lds(
        (const __attribute__((address_space(1))) void*)g,
        (__attribute__((address_space(3))) void*)l, 16, 0, 0);
}

// ---------------- Kernel 1: normalize rows + positives -> fp8 reps ----------
// K-permuted layout per 64-byte block: byte p = qq*16 + h*8 + b holds
// k = b + h*32 + qq*8 -> one b128 LDS read = {k<32 half, k>=32 half}.
__global__ __launch_bounds__(256) void normalize_pos_kernel(
    const float* __restrict__ ei, const float* __restrict__ ej,
    unsigned char* __restrict__ reps, float* __restrict__ pos) {
    const int t = threadIdx.x & 63;
    const int i = blockIdx.x * 4 + (threadIdx.x >> 6);

    const float4* ri = (const float4*)(ei + (size_t)i * DIM);
    const float4* rj = (const float4*)(ej + (size_t)i * DIM);
    float4 a0 = ri[t], a1 = ri[t + 64];
    float4 b0 = rj[t], b1 = rj[t + 64];

    float si  = a0.x*a0.x + a0.y*a0.y + a0.z*a0.z + a0.w*a0.w
              + a1.x*a1.x + a1.y*a1.y + a1.z*a1.z + a1.w*a1.w;
    float sj  = b0.x*b0.x + b0.y*b0.y + b0.z*b0.z + b0.w*b0.w
              + b1.x*b1.x + b1.y*b1.y + b1.z*b1.z + b1.w*b1.w;
    float dij = a0.x*b0.x + a0.y*b0.y + a0.z*b0.z + a0.w*b0.w
              + a1.x*b1.x + a1.y*b1.y + a1.z*b1.z + a1.w*b1.w;

    #pragma unroll
    for (int m = 1; m < 64; m <<= 1) {
        si  += __shfl_xor(si,  m);
        sj  += __shfl_xor(sj,  m);
        dij += __shfl_xor(dij, m);
    }
    float invi = 1.0f / fmaxf(sqrtf(si), 1e-12f);
    float invj = 1.0f / fmaxf(sqrtf(sj), 1e-12f);

    const int off0 = (t >> 4) * 64 + ((t >> 1) & 3) * 16 + ((t >> 3) & 1) * 8 + 4 * (t & 1);

    unsigned wa0 = f2fp8(a0.x*invi) | (f2fp8(a0.y*invi) << 8)
                 | (f2fp8(a0.z*invi) << 16) | (f2fp8(a0.w*invi) << 24);
    unsigned wa1 = f2fp8(a1.x*invi) | (f2fp8(a1.y*invi) << 8)
                 | (f2fp8(a1.z*invi) << 16) | (f2fp8(a1.w*invi) << 24);
    unsigned wb0 = f2fp8(b0.x*invj) | (f2fp8(b0.y*invj) << 8)
                 | (f2fp8(b0.z*invj) << 16) | (f2fp8(b0.w*invj) << 24);
    unsigned wb1 = f2fp8(b1.x*invj) | (f2fp8(b1.y*invj) << 8)
                 | (f2fp8(b1.z*invj) << 16) | (f2fp8(b1.w*invj) << 24);

    unsigned char* wi = reps + (size_t)i * DIM;
    unsigned char* wj = reps + (size_t)(BATCH + i) * DIM;
    *(unsigned*)(wi + off0)       = wa0;
    *(unsigned*)(wi + off0 + 256) = wa1;
    *(unsigned*)(wj + off0)       = wb0;
    *(unsigned*)(wj + off0 + 256) = wb1;
    if (t == 0) pos[i] = dij * invi * invj;
}

// ---------------- Kernel 2: triangle 128x128 cells, fp8 m97/m145-clone -----
// 4 waves, 64x64/wave, 8 K-steps of 64 fp8 bytes, SINGLE 16 KB LDS buffer,
// plain 2-__syncthreads loop (no inline asm; compiler schedules waits),
// 4+ co-resident blocks/CU cover stalls (m114). Zero-conflict swizzle pair
// (proven r6/r15), L/H-pass fp8 MFMA (proven r12/r17), diag mask epilogue.
__global__ __launch_bounds__(256) void simsum_kernel(
    const unsigned char* __restrict__ reps, float* __restrict__ partials) {
    __shared__ unsigned char lds[16384];   // A [128][64B] | B [128][64B]

    int bid = (blockIdx.x & 7) * (NBLK / 8) + (blockIdx.x >> 3);  // 2080 = 8*260
    int rc = 0, b = bid;
    while (b >= NCH - rc) { b -= NCH - rc; ++rc; }
    const int cc = rc + b;                    // rc <= cc
    const bool isDiag = (rc == cc);

    const int tid  = threadIdx.x;
    const int lane = tid & 63;
    const int wave = tid >> 6;                // 0..3
    const int wr = wave >> 1, wc = wave & 1;
    const int s = lane & 15, q = lane >> 4;
    const int rowBase = rc * TILE, colBase = cc * TILE;

    // staging: wave w owns rows [32w, 32w+32) of A and B; pre-swizzled source
    const int lr = lane >> 2;                                  // row-in-16
    const int gb = (((lane & 3) ^ ((lane >> 2) & 3) ^ (lane >> 4)) & 3) * 16;
    const unsigned char* gAw = reps + (size_t)(rowBase + wave * 32 + lr) * DIM + gb;
    const unsigned char* gBw = reps + (size_t)(colBase + wave * 32 + lr) * DIM + gb;

    // ds_read swizzled byte offsets (64 B rows; r6/r15-verified pattern)
    const int sig  = ((s & 3) ^ (s >> 2)) & 3;
    const int koS  = ((q ^ sig) & 3) << 4;
    const int aoff = (wr * 64 + s) * 64 + koS;                 // + m*1024
    const int boff = 8192 + (wc * 64 + s) * 64 + koS;          // + n*1024

    f32x4 acc[4][4];
    #pragma unroll
    for (int m = 0; m < 4; ++m)
        #pragma unroll
        for (int n = 0; n < 4; ++n) acc[m][n] = (f32x4){0.f,0.f,0.f,0.f};

    for (int t = 0; t < NT8; ++t) {
        __syncthreads();                       // prev readers done
        {
            const int kb = t * 64;
            gload16(gAw + kb,            lds + wave * 2048);
            gload16(gAw + 16 * DIM + kb, lds + wave * 2048 + 1024);
            gload16(gBw + kb,            lds + 8192 + wave * 2048);
            gload16(gBw + 16 * DIM + kb, lds + 8192 + wave * 2048 + 1024);
        }
        __syncthreads();                       // publish (compiler drains vmcnt)

        long2v af[4], bf[4];
        #pragma unroll
        for (int m = 0; m < 4; ++m) af[m] = *(const long2v*)((const char*)lds + aoff + m * 1024);
        #pragma unroll
        for (int n = 0; n < 4; ++n) bf[n] = *(const long2v*)((const char*)lds + boff + n * 1024);

        // L-pass (k 0..31 of this step), then H-pass: no acc dependency chains
        #pragma unroll
        for (int m = 0; m < 4; ++m)
            #pragma unroll
            for (int n = 0; n < 4; ++n)
                acc[m][n] = __builtin_amdgcn_mfma_f32_16x16x32_fp8_fp8(
                    af[m][0], bf[n][0], acc[m][n], 0, 0, 0);
        #pragma unroll
        for (int m = 0; m < 4; ++m)
            #pragma unroll
            for (int n = 0; n < 4; ++n)
                acc[m][n] = __builtin_amdgcn_mfma_f32_16x16x32_fp8_fp8(
                    af[m][1], bf[n][1], acc[m][n], 0, 0, 0);
    }

    // ---- epilogue: exp(sim/T); diag masked; row + col sums (r15-verified) ----
    const float SCALE = 2.8853900817779268f;   // 1/(TEMP*ln2) = 2/ln2
    float* red = (float*)lds;                  // [2][128] rowsum | [2][128] colsum
    __syncthreads();
    float colacc[4] = {0.f,0.f,0.f,0.f};
    #pragma unroll
    for (int m = 0; m < 4; ++m) {
        const int lrow0 = wr * 64 + m * 16 + (q << 2);
        const int grow0 = rowBase + lrow0;
        float rs[4] = {0.f,0.f,0.f,0.f};
        #pragma unroll
        for (int n = 0; n < 4; ++n) {
            const int gcol = colBase + wc * 64 + n * 16 + s;
            #pragma unroll
            for (int j = 0; j < 4; ++j) {
                float e = exp2f(acc[m][n][j] * SCALE);
                if (isDiag && (grow0 + j == gcol)) e = 0.f;
                rs[j] += e;
                colacc[n] += e;
            }
        }
        #pragma unroll
        for (int j = 0; j < 4; ++j) {
            float v = rs[j];
            v += __shfl_xor(v, 1); v += __shfl_xor(v, 2);
            v += __shfl_xor(v, 4); v += __shfl_xor(v, 8);
            if (s == 0) red[wc * 128 + lrow0 + j] = v;
        }
    }
    #pragma unroll
    for (int n = 0; n < 4; ++n) {
        float v = colacc[n];
        v += __shfl_xor(v, 16); v += __shfl_xor(v, 32);
        if (q == 0) red[256 + wr * 128 + wc * 64 + n * 16 + s] = v;
    }
    __syncthreads();
    if (tid < TILE) {
        partials[(size_t)cc * NROW + rowBase + tid] = red[tid] + red[128 + tid];
        if (!isDiag)
            partials[(size_t)rc * NROW + colBase + tid] =
                red[256 + tid] + red[384 + tid];
    }
}

// ---------------- Kernel 3a: per-row loss partial sums ----------------
__global__ __launch_bounds__(256) void rowloss_kernel(
    const float* __restrict__ partials, const float* __restrict__ pos,
    double* __restrict__ blocksum) {
    const int t = threadIdx.x;
    const int r = blockIdx.x * 256 + t;
    float denom = 0.f;
    #pragma unroll 16
    for (int c = 0; c < NSLOT; ++c)
        denom += partials[(size_t)c * NROW + r];
    double v = (double)(logf(denom) - 2.0f * pos[r & (BATCH - 1)]);
    __shared__ double redl[256];
    redl[t] = v;
    __syncthreads();
    for (int off = 128; off > 0; off >>= 1) {
        if (t < off) redl[t] += redl[t + off];
        __syncthreads();
    }
    if (t == 0) blocksum[blockIdx.x] = redl[0];
}

__global__ void final2_kernel(const double* __restrict__ blocksum,
                              float* __restrict__ out) {
    if (threadIdx.x == 0) {
        double ssum = 0.0;
        #pragma unroll
        for (int i = 0; i < NROW / 256; ++i) ssum += blocksum[i];
        out[0] = (float)(ssum / (double)NROW);
    }
}

extern "C" void kernel_launch(void* const* d_in, const int* in_sizes, int n_in,
                              void* d_out, int out_size, void* d_ws, size_t ws_size,
                              hipStream_t stream) {
    const float* ei = (const float*)d_in[0];
    const float* ej = (const float*)d_in[1];
    float* out = (float*)d_out;

    unsigned char* reps = (unsigned char*)d_ws;                         // 4 MB fp8
    float* pos      = (float*)((char*)d_ws + (size_t)NROW * DIM);       // 16 KB
    float* partials = pos + BATCH;                                      // 64*8192*4 = 2 MB
    double* blocksum = (double*)(partials + (size_t)NSLOT * NROW);

    normalize_pos_kernel<<<BATCH / 4, 256, 0, stream>>>(ei, ej, reps, pos);
    simsum_kernel<<<NBLK, 256, 0, stream>>>(reps, partials);
    rowloss_kernel<<<NROW / 256, 256, 0, stream>>>(partials, pos, blocksum);
    final2_kernel<<<1, 64, 0, stream>>>(blocksum, out);
}